// Round 5
// baseline (84.385 us; speedup 1.0000x reference)
//
#include <hip/hip_runtime.h>

#define HH 128
#define WW 128
#define CC 64
#define KD 16
#define HW (HH * WW)
#define HWB (HW * 4)
#define TOTBYTES (4u * CC * HW * 4u)   // B=4 * C=64 * H*W * 4B
#define OOB_SENT 0x40000000            // always-OOB voffset -> HW returns 0

typedef __attribute__((ext_vector_type(4))) int   int32x4_t;
typedef __attribute__((ext_vector_type(4))) float floatx4;
typedef _Float16 f16x8 __attribute__((ext_vector_type(8)));

__device__ floatx4 llvm_amdgcn_raw_buffer_load_v4f32(int32x4_t srsrc, int voffset,
                                                     int soffset, int aux)
    __asm("llvm.amdgcn.raw.buffer.load.v4f32");
__device__ float llvm_amdgcn_raw_buffer_load_f32(int32x4_t srsrc, int voffset,
                                                 int soffset, int aux)
    __asm("llvm.amdgcn.raw.buffer.load.f32");

__device__ inline int32x4_t make_srd(const void* p, unsigned bytes) {
    const unsigned long long a = (unsigned long long)p;
    int32x4_t r;
    r.x = (int)(a & 0xffffffffull);
    r.y = (int)(a >> 32);
    r.z = (int)bytes;
    r.w = 0x00020000;
    return r;
}

#if __has_builtin(__builtin_amdgcn_exp2f)
#define FAST_EXP2(x) __builtin_amdgcn_exp2f(x)
#define KLOG2E 1.44269504088896340736f
#else
#define FAST_EXP2(x) __expf(x)
#define KLOG2E 1.0f
#endif

// Block: 512 threads = 8 waves over one 16(w) x 4(h) pixel tile.
// Phase 0: stage x halo-window (6x18 x 64c) + repacked Wk into LDS as fp16.
// Phase 1: k-conv on MFMA: wave g=(r=g&3, cv=g>>2) does 9x mfma_16x16x32_f16
//          (tap-accumulated, K=32 channels) -> partial D[16d x 16px] -> LDS.
// Phase 2: 2-way reduce + bias + relu -> k; then q-conv + softmax (as R4).
// LDS: xt 14336 B + wk 18432 B + part 8192 B = 40960 B -> 4 blocks/CU.
__global__ __launch_bounds__(512, 8) void gatev_fused(
    const float* __restrict__ x, const float* __restrict__ y,
    const float* __restrict__ z,
    const float* __restrict__ Wq, const float* __restrict__ bq,
    const float* __restrict__ Wk, const float* __restrict__ bk,
    const float* __restrict__ wv, const float* __restrict__ bv,
    float* __restrict__ out)
{
    __shared__ __align__(16) unsigned char smem[40960];
    unsigned short* xt   = (unsigned short*)smem;            // [pos<=112][64c] fp16, swizzled
    unsigned short* wkl  = (unsigned short*)(smem + 14336);  // [9t][16d][64c] fp16, swizzled
    float*          part = (float*)(smem + 32768);           // [2cv][16d][64px] f32; [0] becomes k

    const int tid  = threadIdx.x;
    const int g    = __builtin_amdgcn_readfirstlane(tid >> 6);
    const int lane = tid & 63;
    const int px   = lane & 15, py = lane >> 4;
    const int b    = blockIdx.z;
    const int h0   = blockIdx.y * 4;
    const int w0   = blockIdx.x * 16;
    const int h    = h0 + py;
    const int w    = w0 + px;
    const int pix  = h * WW + w;

    const int32x4_t rx = make_srd(x, TOTBYTES);
    const int32x4_t ry = make_srd(y, TOTBYTES);
    const int32x4_t rz = make_srd(z, TOTBYTES);

    const int base = b * CC * HWB;

    // ---------------- phase 0a: stage x halo window -> fp16 LDS -------------
    // dest linear elem = pos*64 + c, pos = row6*18 + col18 (halo at h0-1, w0-1)
#pragma unroll
    for (int rep = 0; rep < 7; ++rep) {
        const int idx2 = tid + rep * 512;          // pair index
        const int e0   = idx2 * 2;
        const int c    = e0 & 63;                  // even
        const int pos  = e0 >> 6;
        if (pos < 108) {
            const int row = pos / 18, col = pos - row * 18;
            const int ir = h0 - 1 + row, ic = w0 - 1 + col;
            const int voff = ((unsigned)ir < (unsigned)HH && (unsigned)ic < (unsigned)WW)
                             ? (ir * WW + ic) * 4 : OOB_SENT;
            const float a = llvm_amdgcn_raw_buffer_load_f32(rx, voff, base + c * HWB, 0);
            const float bv2 = llvm_amdgcn_raw_buffer_load_f32(rx, voff, base + (c + 1) * HWB, 0);
            const unsigned short ua = __builtin_bit_cast(unsigned short, (_Float16)a);
            const unsigned short ub = __builtin_bit_cast(unsigned short, (_Float16)bv2);
            const int gsw  = ((c >> 3) ^ (col & 7));          // granule swizzle by col
            const int addr = pos * 64 + gsw * 8 + (c & 7);    // element index (even)
            *(unsigned*)(xt + addr) = (unsigned)ua | ((unsigned)ub << 16);
        }
    }

    // ---------------- phase 0b: repack Wk -> fp16 LDS [t][d][c] -------------
#pragma unroll
    for (int rep = 0; rep < 9; ++rep) {
        const int idx2 = tid + rep * 512;          // pair index, 4608 pairs total
        const int e0   = idx2 * 2;
        const int c    = e0 & 63;                  // even
        const int d    = (e0 >> 6) & 15;
        const int t    = e0 >> 10;                 // [0,9)
        const float a   = Wk[(d * CC + c) * 9 + t];
        const float b2  = Wk[(d * CC + c + 1) * 9 + t];
        const unsigned short ua = __builtin_bit_cast(unsigned short, (_Float16)a);
        const unsigned short ub = __builtin_bit_cast(unsigned short, (_Float16)b2);
        const int gsw  = ((c >> 3) ^ (d & 7));               // granule swizzle by d
        const int addr = (t * 16 + d) * 64 + gsw * 8 + (c & 7);
        *(unsigned*)(wkl + addr) = (unsigned)ua | ((unsigned)ub << 16);
    }
    __syncthreads();

    // ---------------- phase 1: k-conv via MFMA ------------------------------
    {
        const int r  = g & 3;        // px row-tile
        const int cv = g >> 2;       // c-half
        const int m  = lane & 15;    // A: row d   | B: col px
        const int q  = lane >> 4;    // K quadrant: k = q*8 + j

        floatx4 acc = {0.f, 0.f, 0.f, 0.f};
#pragma unroll
        for (int t = 0; t < 9; ++t) {
            const int trow = t / 3, tcol = t % 3;
            // A fragment: Wk[t][d=m][k = cv*32 + q*8 + j]
            const int ga = (cv * 4 + q) ^ (m & 7);
            const f16x8 af = *(const f16x8*)(wkl + ((t * 16 + m) * 64 + ga * 8));
            // B fragment: xt[row=r+trow][col=m+tcol][same k]
            const int col = m + tcol;
            const int pos = (r + trow) * 18 + col;
            const int gb  = (cv * 4 + q) ^ (col & 7);
            const f16x8 bf = *(const f16x8*)(xt + (pos * 64 + gb * 8));
            acc = __builtin_amdgcn_mfma_f32_16x16x32_f16(af, bf, acc, 0, 0, 0);
        }
        // D layout: col(px16) = lane&15 = m, row(d) = q*4 + i
        const int pbase = (cv * 16 + q * 4) * 64 + r * 16 + m;
#pragma unroll
        for (int i = 0; i < 4; ++i)
            part[pbase + i * 64] = acc[i];
    }
    __syncthreads();

    // ---------------- reduce 2 c-halves -> k[d][px64] (in place) ------------
#pragma unroll
    for (int rep = 0; rep < 2; ++rep) {
        const int idx = tid + rep * 512;           // d*64 + px64
        const int d   = idx >> 6;
        const float s = part[idx] + part[1024 + idx];
        part[idx] = fmaxf(s + bk[d], 0.f) * KLOG2E;
    }
    __syncthreads();

    // ---------------- phase 2: q, v, softmax-attention, 8 c's per wave ------
    // One float4 per tap-row at col max(w-1,0) covers the 3 horizontal taps.
    const int colb = (w > 0 ? w - 1 : 0) * 4;
    int rowB[3];
#pragma unroll
    for (int r3 = 0; r3 < 3; ++r3) {
        const int rr = h - 1 + r3;
        rowB[r3] = (rr >= 0 && rr < HH) ? rr * WW * 4 + colb : OOB_SENT;
    }
    const float mL = (w > 0) ? 1.f : 0.f;
    const float mR = (w < WW - 1) ? 1.f : 0.f;
    const bool  w0e = (w == 0);

    const int c0 = __builtin_amdgcn_readfirstlane(g * 8);

    float qv[8], zv[8];
#pragma unroll 2
    for (int ci = 0; ci < 8; ++ci) {
        const int c  = c0 + ci;
        const int so = base + c * HWB;
        const float* wq = Wq + c * 9;              // uniform -> s_load
        float a = 0.f;
#pragma unroll
        for (int r3 = 0; r3 < 3; ++r3) {
            const floatx4 f = llvm_amdgcn_raw_buffer_load_v4f32(ry, rowB[r3], so, 0);
            const float tL = f.x * mL;
            const float tC = w0e ? f.x : f.y;
            const float tR = (w0e ? f.y : f.z) * mR;
            a = fmaf(wq[r3 * 3 + 0], tL, a);
            a = fmaf(wq[r3 * 3 + 1], tC, a);
            a = fmaf(wq[r3 * 3 + 2], tR, a);
        }
        qv[ci] = fmaxf(a + bq[c], 0.f);
        zv[ci] = llvm_amdgcn_raw_buffer_load_f32(rz, pix * 4, so, 0);
    }

    float num[8], den[8];
#pragma unroll
    for (int ci = 0; ci < 8; ++ci) { num[ci] = 0.f; den[ci] = 0.f; }

#pragma unroll
    for (int d = 0; d < KD; ++d) {
        const float kl  = part[d * 64 + lane];     // lane-contiguous: conflict-free
        const float wvd = wv[d];                   // SGPR
        const float bvd = bv[d];                   // SGPR
#pragma unroll
        for (int ci = 0; ci < 8; ++ci) {
            const float e = FAST_EXP2(qv[ci] * kl);
            const float v = fmaxf(zv[ci] * wvd + bvd, 0.f);
            num[ci] = fmaf(e, v, num[ci]);
            den[ci] += e;
        }
    }

    float* ob = out + (size_t)b * CC * HW;
#pragma unroll
    for (int ci = 0; ci < 8; ++ci)
        ob[(c0 + ci) * HW + pix] = __fdividef(num[ci], den[ci]);
}

extern "C" void kernel_launch(void* const* d_in, const int* in_sizes, int n_in,
                              void* d_out, int out_size, void* d_ws, size_t ws_size,
                              hipStream_t stream) {
    const float* x  = (const float*)d_in[0];
    const float* y  = (const float*)d_in[1];
    const float* z  = (const float*)d_in[2];
    const float* Wq = (const float*)d_in[3];
    const float* bq = (const float*)d_in[4];
    const float* Wk = (const float*)d_in[5];
    const float* bk = (const float*)d_in[6];
    const float* wv = (const float*)d_in[7];
    const float* bv = (const float*)d_in[8];
    float* out = (float*)d_out;

    dim3 grid(WW / 16, HH / 4, 4);   // 1024 blocks
    dim3 block(512);                 // 8 waves
    hipLaunchKernelGGL(gatev_fused, grid, block, 0, stream,
                       x, y, z, Wq, bq, Wk, bk, wv, bv, out);
}

// Round 6
// 48.505 us; speedup vs baseline: 1.7397x; 1.7397x over previous
//
#include <hip/hip_runtime.h>

#define HH 128
#define WW 128
#define CC 64
#define KD 16
#define HW (HH * WW)
#define HWB (HW * 4)
#define TOTBYTES (4u * CC * HW * 4u)   // B=4 * C=64 * H*W * 4B = 16.78 MB
#define OOB_SENT 0x40000000            // always-OOB voffset -> HW returns 0

typedef __attribute__((ext_vector_type(4))) int   int32x4_t;
typedef __attribute__((ext_vector_type(4))) float floatx4;

__device__ floatx4 llvm_amdgcn_raw_buffer_load_v4f32(int32x4_t srsrc, int voffset,
                                                     int soffset, int aux)
    __asm("llvm.amdgcn.raw.buffer.load.v4f32");
__device__ float llvm_amdgcn_raw_buffer_load_f32(int32x4_t srsrc, int voffset,
                                                 int soffset, int aux)
    __asm("llvm.amdgcn.raw.buffer.load.f32");

__device__ inline int32x4_t make_srd(const void* p, unsigned bytes) {
    const unsigned long long a = (unsigned long long)p;
    int32x4_t r;
    r.x = (int)(a & 0xffffffffull);
    r.y = (int)(a >> 32);
    r.z = (int)bytes;
    r.w = 0x00020000;
    return r;
}

#if __has_builtin(__builtin_amdgcn_exp2f)
#define FAST_EXP2(x) __builtin_amdgcn_exp2f(x)
#define KLOG2E 1.44269504088896340736f
#else
#define FAST_EXP2(x) __expf(x)
#define KLOG2E 1.0f
#endif

// Block: 512 threads = 8 waves over one 16(w) x 4(h) pixel tile.
// Phase 0: stage ALL of Wk (36 KB) into LDS, repacked per-wave-contiguous
//          [g][ci][d][t] (coalesced global reads; one-time).
// Phase 1: wave g reads channels [8g,8g+8) of x (double-buffered dwordx4 rows)
//          and accumulates partial k for ALL 16 d's; weights come from LDS via
//          uniform-address ds_read_b128 broadcast (no scalar-K$ thrash).
// Then:    partials -> LDS (reusing the weight region), 8-way reduce -> k.
// Phase 2: wave g: q-conv + v + softmax for channels [8g,8g+8)  (same as R4).
// LDS: 36 KB -> 4 blocks/CU; __launch_bounds__(512,8) -> <=64 VGPR.
__global__ __launch_bounds__(512, 8) void gatev_fused(
    const float* __restrict__ x, const float* __restrict__ y,
    const float* __restrict__ z,
    const float* __restrict__ Wq, const float* __restrict__ bq,
    const float* __restrict__ Wk, const float* __restrict__ bk,
    const float* __restrict__ wv, const float* __restrict__ bv,
    float* __restrict__ out)
{
    __shared__ float wk_lds[9216];   // 36 KB; weights -> partials -> k (aliased)

    const int tid  = threadIdx.x;
    const int g    = __builtin_amdgcn_readfirstlane(tid >> 6);
    const int lane = tid & 63;
    const int px   = lane & 15, py = lane >> 4;
    const int b    = blockIdx.z;
    const int h    = blockIdx.y * 4 + py;
    const int w    = blockIdx.x * 16 + px;
    const int pix  = h * WW + w;

    const int32x4_t rx = make_srd(x, TOTBYTES);
    const int32x4_t ry = make_srd(y, TOTBYTES);
    const int32x4_t rz = make_srd(z, TOTBYTES);

    // One float4 per tap-row at col max(w-1,0) covers the 3 horizontal taps.
    const int colb = (w > 0 ? w - 1 : 0) * 4;
    int rowB[3];
#pragma unroll
    for (int r = 0; r < 3; ++r) {
        const int rr = h - 1 + r;
        rowB[r] = (rr >= 0 && rr < HH) ? rr * WW * 4 + colb : OOB_SENT;
    }
    const float mL = (w > 0) ? 1.f : 0.f;
    const float mR = (w < WW - 1) ? 1.f : 0.f;
    const bool  w0e = (w == 0);

    const int base = b * CC * HWB;
    const int c0   = __builtin_amdgcn_readfirstlane(g * 8);

    // ---------------- phase 0: stage Wk -> LDS, repacked [g][ci][d][9] ------
    // src linear s = (d*64 + c)*9 + t ; dst = (c>>3)*1152 + (c&7)*144 + d*9 + t
#pragma unroll
    for (int p = 0; p < 18; ++p) {
        const int s   = p * 512 + tid;           // coalesced across lanes
        const int d   = s / 576;
        const int rem = s - d * 576;
        const int c   = rem / 9;
        const int t   = rem - c * 9;
        wk_lds[(c >> 3) * 1152 + (c & 7) * 144 + d * 9 + t] = Wk[s];
    }
    __syncthreads();

    // ---------------- phase 1: partial k over this wave's 8 channels --------
    float acc[KD];
#pragma unroll
    for (int d = 0; d < KD; ++d) acc[d] = 0.f;

    auto load3 = [&](floatx4 (&f)[3], int so) {
#pragma unroll
        for (int r = 0; r < 3; ++r)
            f[r] = llvm_amdgcn_raw_buffer_load_v4f32(rx, rowB[r], so, 0);
    };
    auto compute = [&](const floatx4 (&f)[3], int wb) {
        float tp[9];
#pragma unroll
        for (int r = 0; r < 3; ++r) {
            tp[r * 3 + 0] = f[r].x * mL;
            tp[r * 3 + 1] = w0e ? f[r].x : f[r].y;
            tp[r * 3 + 2] = (w0e ? f[r].y : f[r].z) * mR;
        }
#pragma unroll
        for (int i = 0; i < 36; ++i) {           // uniform-address broadcast read
            const floatx4 wf = *(const floatx4*)&wk_lds[wb + i * 4];
#pragma unroll
            for (int j = 0; j < 4; ++j) {
                const int flat = i * 4 + j;      // d = flat/9, t = flat%9 (static)
                acc[flat / 9] = fmaf(wf[j], tp[flat % 9], acc[flat / 9]);
            }
        }
    };

    const int wbase = g * 1152;
    floatx4 f0[3], f1[3];
    load3(f0, base + c0 * HWB);
#pragma unroll
    for (int cp = 0; cp < 4; ++cp) {
        load3(f1, base + (c0 + 2 * cp + 1) * HWB);       // prefetch odd channel
        compute(f0, wbase + (2 * cp) * 144);
        load3(f0, base + (c0 + 2 * cp + 2) * HWB);       // prefetch next even (tail: SRD-bounded)
        compute(f1, wbase + (2 * cp + 1) * 144);
    }
    __syncthreads();                                     // all weight reads done

    // partials overwrite the weight region: part[g][d][lane]
#pragma unroll
    for (int d = 0; d < KD; ++d)
        wk_lds[g * (KD * 64) + d * 64 + lane] = acc[d];
    __syncthreads();

    // ---------------- reduce 8 partials -> k[d][px64] (in place) ------------
#pragma unroll
    for (int rep = 0; rep < 2; ++rep) {
        const int idx = tid + rep * 512;                 // = d*64 + px64
        float s = wk_lds[idx];
#pragma unroll
        for (int gg = 1; gg < 8; ++gg) s += wk_lds[gg * (KD * 64) + idx];
        const int d = idx >> 6;
        wk_lds[idx] = fmaxf(s + bk[d], 0.f) * KLOG2E;
    }
    __syncthreads();

    // ---------------- phase 2: q, v, softmax-attention, 8 c's per wave ------
    float qv[8], zv[8];
#pragma unroll 2
    for (int ci = 0; ci < 8; ++ci) {
        const int c  = c0 + ci;
        const int so = base + c * HWB;
        const float* wq = Wq + c * 9;                    // uniform -> s_load (small)
        float a = 0.f;
#pragma unroll
        for (int r = 0; r < 3; ++r) {
            const floatx4 f = llvm_amdgcn_raw_buffer_load_v4f32(ry, rowB[r], so, 0);
            const float tL = f.x * mL;
            const float tC = w0e ? f.x : f.y;
            const float tR = (w0e ? f.y : f.z) * mR;
            a = fmaf(wq[r * 3 + 0], tL, a);
            a = fmaf(wq[r * 3 + 1], tC, a);
            a = fmaf(wq[r * 3 + 2], tR, a);
        }
        qv[ci] = fmaxf(a + bq[c], 0.f);
        zv[ci] = llvm_amdgcn_raw_buffer_load_f32(rz, pix * 4, so, 0);
    }

    float num[8], den[8];
#pragma unroll
    for (int ci = 0; ci < 8; ++ci) { num[ci] = 0.f; den[ci] = 0.f; }

#pragma unroll
    for (int d = 0; d < KD; ++d) {
        const float kl  = wk_lds[d * 64 + lane];         // lane-contiguous, conflict-free
        const float wvd = wv[d];                         // SGPR
        const float bvd = bv[d];                         // SGPR
#pragma unroll
        for (int ci = 0; ci < 8; ++ci) {
            const float e = FAST_EXP2(qv[ci] * kl);
            const float v = fmaxf(zv[ci] * wvd + bvd, 0.f);
            num[ci] = fmaf(e, v, num[ci]);
            den[ci] += e;
        }
    }

    float* ob = out + (size_t)b * CC * HW;
#pragma unroll
    for (int ci = 0; ci < 8; ++ci)
        ob[(c0 + ci) * HW + pix] = __fdividef(num[ci], den[ci]);
}

extern "C" void kernel_launch(void* const* d_in, const int* in_sizes, int n_in,
                              void* d_out, int out_size, void* d_ws, size_t ws_size,
                              hipStream_t stream) {
    const float* x  = (const float*)d_in[0];
    const float* y  = (const float*)d_in[1];
    const float* z  = (const float*)d_in[2];
    const float* Wq = (const float*)d_in[3];
    const float* bq = (const float*)d_in[4];
    const float* Wk = (const float*)d_in[5];
    const float* bk = (const float*)d_in[6];
    const float* wv = (const float*)d_in[7];
    const float* bv = (const float*)d_in[8];
    float* out = (float*)d_out;

    dim3 grid(WW / 16, HH / 4, 4);   // 1024 blocks = 4 blocks/CU
    dim3 block(512);                 // 8 waves
    hipLaunchKernelGGL(gatev_fused, grid, block, 0, stream,
                       x, y, z, Wq, bq, Wk, bk, wv, bv, out);
}